// Round 22
// baseline (1700.337 us; speedup 1.0000x reference)
//
#include <hip/hip_runtime.h>
#include <hip/hip_fp16.h>
#include <cmath>

#define MIN_NORM 1e-15f
#define RCPF(x)  __builtin_amdgcn_rcpf(x)
#define SQRTF(x) __builtin_amdgcn_sqrtf(x)
#define RSQF(x)  __builtin_amdgcn_rsqf(x)

#if defined(__has_builtin)
#if __has_builtin(__builtin_amdgcn_fdot2)
#define HAVE_FDOT2 1
#endif
#endif

typedef _Float16 h2_t __attribute__((ext_vector_type(2)));

__device__ __forceinline__ float fdot2_acc(__half2 a, __half2 b, float c) {
#ifdef HAVE_FDOT2
    h2_t av, bv;
    __builtin_memcpy(&av, &a, 4);
    __builtin_memcpy(&bv, &b, 4);
    return __builtin_amdgcn_fdot2(av, bv, c, false);
#else
    float2 fa = __half22float2(a);
    float2 fb = __half22float2(b);
    return fmaf(fa.x, fb.x, fmaf(fa.y, fb.y, c));
#endif
}

template<int CTRL>
__device__ __forceinline__ float dpp_add(float v) {
    return __int_as_float(__builtin_amdgcn_update_dpp(0, __float_as_int(v), CTRL, 0xF, 0xF, false));
}

__device__ __forceinline__ float rsum16(float v) {
    v += dpp_add<0x121>(v);
    v += dpp_add<0x122>(v);
    v += dpp_add<0x124>(v);
    v += dpp_add<0x128>(v);
    return v;
}

__device__ __forceinline__ float rsum8(float v) {
    v += dpp_add<0xB1>(v);   // quad_perm xor1
    v += dpp_add<0x4E>(v);   // quad_perm xor2
    v += dpp_add<0x141>(v);  // row_half_mirror
    return v;
}

__device__ __forceinline__ float tanh_fast(float x) {
    float ex = __expf(fminf(2.f * x, 30.f));
    return (ex - 1.f) * RCPF(ex + 1.f);
}

// ---- fused pass 1: [0,EB) count | [EB,EB+PG) entity tables + EH | rest rel ----
__global__ __launch_bounds__(256) void k_pass1(
    const int*    __restrict__ head,
    const float4* __restrict__ ent,
    const float4* __restrict__ rel,
    int*     __restrict__ C,
    float2*  __restrict__ Th1,
    float2*  __restrict__ Tt1,
    float2*  __restrict__ RelC1,
    float2*  __restrict__ RelC2,
    __half2* __restrict__ EH2,     // [N*32]
    __half2* __restrict__ RelH2,   // [NR*32]
    float ILAM2, int E, int N, int NR, int EB, int PG)
{
    int b = (int)blockIdx.x;
    if (b < EB) {
        int i = b * 256 + (int)threadIdx.x;
        if (i < E) atomicAdd(&C[head[i]], 1);
    } else if (b < EB + PG) {
        int gid = ((b - EB) * 256 + (int)threadIdx.x) >> 4;
        int g   = (int)threadIdx.x & 15;
        if (gid >= N) return;
        float4 v = ent[(size_t)gid * 16 + g];
        EH2[(size_t)gid * 32 + 2 * g]     = __floats2half2_rn(v.x, v.y);
        EH2[(size_t)gid * 32 + 2 * g + 1] = __floats2half2_rn(v.z, v.w);
        float n2 = rsum16(v.x * v.x + v.y * v.y + v.z * v.z + v.w * v.w);
        if (g == 0) {
            float nh     = fmaxf(SQRTF(fmaxf(n2, 0.f)), MIN_NORM);
            float inv_nh = RCPF(nh);
            float th     = tanh_fast(nh);
            Th1[gid] = make_float2(th * inv_nh, th * th);
            Tt1[gid] = make_float2(nh, inv_nh);
        }
    } else {
        int gid = ((b - EB - PG) * 256 + (int)threadIdx.x) >> 4;
        int g   = (int)threadIdx.x & 15;
        if (gid >= NR) return;
        float4 v = rel[(size_t)gid * 16 + g];
        RelH2[(size_t)gid * 32 + 2 * g]     = __floats2half2_rn(v.x, v.y);
        RelH2[(size_t)gid * 32 + 2 * g + 1] = __floats2half2_rn(v.z, v.w);
        float n2 = rsum16(v.x * v.x + v.y * v.y + v.z * v.z + v.w * v.w);
        if (g == 0) {
            float nr = fmaxf(SQRTF(n2), MIN_NORM);
            float inv_nr = RCPF(nr);
            RelC1[gid] = make_float2(nr, inv_nr);
            float thr2 = tanh_fast(ILAM2 * nr);
            RelC2[gid] = make_float2(thr2 * inv_nr, thr2 * thr2);
        }
    }
}

// ---- scan1: per-block inclusive scan C -> T, block sums -> BS, + degree hist ----
__global__ __launch_bounds__(256) void k_scan1(const int* __restrict__ C,
                                               int* __restrict__ T,
                                               int* __restrict__ BS,
                                               int* __restrict__ DH, int N) {
    __shared__ int lds[256];
    __shared__ int lh[64];
    if (threadIdx.x < 64) lh[threadIdx.x] = 0;
    int i = blockIdx.x * 256 + (int)threadIdx.x;
    int v = (i < N) ? C[i] : 0;
    lds[threadIdx.x] = v;
    __syncthreads();
    for (int off = 1; off < 256; off <<= 1) {
        int add = (threadIdx.x >= (unsigned)off) ? lds[threadIdx.x - off] : 0;
        __syncthreads();
        lds[threadIdx.x] += add;
        __syncthreads();
    }
    if (i < N) {
        T[i] = lds[threadIdx.x];
        int bd = 63 - min(v, 63);
        atomicAdd(&lh[bd], 1);
    }
    if (threadIdx.x == 255) BS[blockIdx.x] = lds[255];
    __syncthreads();
    if (threadIdx.x < 64 && lh[threadIdx.x] > 0)
        atomicAdd(&DH[threadIdx.x], lh[threadIdx.x]);
}

// ---- scan2: block 0 scans BS[nb]; block 1 scans DH->DB ----
__global__ __launch_bounds__(1024) void k_scan2(int* __restrict__ BS,
                                                const int* __restrict__ DH,
                                                int* __restrict__ DB, int nb) {
    if (blockIdx.x == 0) {
        __shared__ int lds[1024];
        int v = ((int)threadIdx.x < nb) ? BS[threadIdx.x] : 0;
        lds[threadIdx.x] = v;
        __syncthreads();
        for (int off = 1; off < 1024; off <<= 1) {
            int add = (threadIdx.x >= (unsigned)off) ? lds[threadIdx.x - off] : 0;
            __syncthreads();
            lds[threadIdx.x] += add;
            __syncthreads();
        }
        if ((int)threadIdx.x < nb) BS[threadIdx.x] = lds[threadIdx.x] - v;
    } else {
        __shared__ int lds[64];
        if (threadIdx.x >= 64) return;
        int t = (int)threadIdx.x;
        int v = DH[t];
        lds[t] = v;
        __syncthreads();
        for (int off = 1; off < 64; off <<= 1) {
            int add = (t >= off) ? lds[t - off] : 0;
            __syncthreads();
            lds[t] += add;
            __syncthreads();
        }
        DB[t] = lds[t] - v;
    }
}

// ---- scan3: ordered offsets OC={beg,cnt}, P=beg ----
__global__ __launch_bounds__(256) void k_scan3(const int* __restrict__ C,
                                               const int* __restrict__ T,
                                               const int* __restrict__ BS,
                                               int2* __restrict__ OC,
                                               int* __restrict__ P, int N) {
    int i = blockIdx.x * 256 + (int)threadIdx.x;
    if (i < N) {
        int c = C[i];
        int beg = T[i] - c + BS[blockIdx.x];
        OC[i] = make_int2(beg, c);
        P[i] = beg;
    }
}

// ---- bucket pass: [0,NB) perm dscatter | [NB,..) bucket edges into region queues ----
// Queue r holds edges whose head is in [r*RSZ,(r+1)*RSZ); capacity CAP each,
// indexed BK[r*CAP + pos]. Overflow (statistically impossible for uniform heads,
// but guarded) falls back to direct scatter via P.
__global__ __launch_bounds__(256) void k_bucket(
    const int* __restrict__ C,
    int*       __restrict__ DB,
    int*       __restrict__ perm,
    const int* __restrict__ head,
    const int* __restrict__ tail,
    const int* __restrict__ etype,
    int*       __restrict__ P,
    int*       __restrict__ rec,
    int*       __restrict__ BCUR,   // [8]
    int2*      __restrict__ BK,     // [8*CAP]
    int N, int E, int NB, int RSZ, int CAP)
{
    int b = (int)blockIdx.x;
    if (b < NB) {
        __shared__ int lh[64];
        __shared__ int lbase[64];
        if (threadIdx.x < 64) lh[threadIdx.x] = 0;
        __syncthreads();
        int i = b * 256 + (int)threadIdx.x;
        int bd = -1, lr = 0;
        if (i < N) {
            bd = 63 - min(C[i], 63);
            lr = atomicAdd(&lh[bd], 1);
        }
        __syncthreads();
        if (threadIdx.x < 64 && lh[threadIdx.x] > 0)
            lbase[threadIdx.x] = atomicAdd(&DB[threadIdx.x], lh[threadIdx.x]);
        __syncthreads();
        if (bd >= 0) perm[lbase[bd] + lr] = i;
    } else {
        int i = (b - NB) * 256 + (int)threadIdx.x;
        int lane = (int)threadIdx.x & 63;
        bool ok = i < E;
        int h = 0, pk = 0, reg = -1;
        if (ok) {
            h = head[i];
            pk = tail[i] | ((etype[i] - 1) << 20);
            reg = min(h / RSZ, 7);
        }
#pragma unroll
        for (int r = 0; r < 8; ++r) {
            unsigned long long m = __ballot(reg == r);
            if (m) {
                int cnt = __popcll(m);
                int leader = (int)(__ffsll((unsigned long long)m) - 1);
                int bs = 0;
                if (lane == leader) bs = atomicAdd(&BCUR[r], cnt);
                bs = __shfl(bs, leader, 64);
                if (reg == r) {
                    int pos = bs + (int)__popcll(m & ((1ULL << lane) - 1ULL));
                    if (pos < CAP) {
                        BK[(size_t)r * CAP + pos] = make_int2(h, pk);
                    } else {
                        int p = atomicAdd(&P[h], 1);   // overflow fallback
                        rec[p] = pk;
                    }
                }
            }
        }
    }
}

// ---- scatter2: region-local drain of queues into CSR rec ----
__global__ __launch_bounds__(256) void k_scatter2(
    const int2* __restrict__ BK,
    const int*  __restrict__ BCUR,
    int*        __restrict__ P,
    int*        __restrict__ rec,
    int CAP, int S)
{
    int r = (int)blockIdx.x / S;
    int j = (int)blockIdx.x % S;
    int cnt = min(BCUR[r], CAP);
    const int2* q = BK + (size_t)r * CAP;
    int step = S * 256;
    for (int idx = j * 256 + (int)threadIdx.x; idx < cnt; idx += step) {
        int2 e = q[idx];
        int pos = atomicAdd(&P[e.x], 1);
        rec[pos] = e.y;
    }
}

// ---- hop kernel: 8-lane group/head; contiguous dims {8l..8l+7}; one dwordx4
//      per row; 2-deep pipeline; fdot2 dots; fused epilogue (R20, unchanged) ----
template<bool HOP2>
__global__ __launch_bounds__(256) void rgat_hop_kernel(
    const __half2* __restrict__ e2,
    const __half2* __restrict__ rel2,
    const float2*  __restrict__ Th1,
    const float2*  __restrict__ Tt1,
    const float2*  __restrict__ Tt2,
    const float2*  __restrict__ RelC1,
    const float2*  __restrict__ RelC2,
    const int*     __restrict__ rec,
    const int2*    __restrict__ OC,
    const int*     __restrict__ perm,
    const float*   __restrict__ entf,
    float*         __restrict__ outf,
    __half2*       __restrict__ Ah2w,
    float2*        __restrict__ Tt2w,
    float SCP2, float P2C, float ILAM2, int N)
{
    int tid  = blockIdx.x * 256 + (int)threadIdx.x;
    int slot = tid >> 3;
    int l    = (int)threadIdx.x & 7;
    bool act = slot < N;
    int h    = perm[act ? slot : 0];

    int2 oc = OC[h];
    int beg = act ? oc.x : 0;
    int end = act ? (oc.x + oc.y) : 0;

    float4 hraw = *reinterpret_cast<const float4*>(e2 + (size_t)h * 32 + 4 * l);
    __half2 hh[4];
    float hv[8];
    {
        __builtin_memcpy(hh, &hraw, 16);
#pragma unroll
        for (int k = 0; k < 4; ++k) {
            float2 f = __half22float2(hh[k]);
            hv[2 * k] = f.x; hv[2 * k + 1] = f.y;
        }
    }

    float scp, p2;
    if constexpr (HOP2) {
        scp = SCP2; p2 = P2C;
    } else {
        float2 th = Th1[h];
        scp = th.x; p2 = th.y;
    }
    float bet  = fmaxf(1.f - p2, MIN_NORM);
    float ilam = RCPF(bet);
    float bet2 = bet * bet;

    float acc[8];
#pragma unroll
    for (int k = 0; k < 8; ++k) acc[k] = 0.f;

    float4 tA, rA, tB, rB;
    float2 tvA, rvA, tvB, rvB;

    auto LD = [&](int i, float4& T4, float4& R4, float2& TV, float2& RV) {
        int rc = rec[i];
        int ti = rc & 0xFFFFF;
        int ri = rc >> 20;
        T4 = *reinterpret_cast<const float4*>(e2   + (size_t)ti * 32 + 4 * l);
        R4 = *reinterpret_cast<const float4*>(rel2 + (size_t)ri * 32 + 4 * l);
        if constexpr (HOP2) { TV = Tt2[ti]; RV = RelC2[ri]; }
        else               { TV = Tt1[ti]; RV = RelC1[ri]; }
    };

    auto COMPUTE = [&](const float4& T4, const float4& R4, float2 tv, float2 rv) {
        __half2 t2[4], r2[4];
        __builtin_memcpy(t2, &T4, 16);
        __builtin_memcpy(r2, &R4, 16);

        float pht = 0.f, phr = 0.f, ptr_ = 0.f;
#pragma unroll
        for (int k = 0; k < 4; ++k) {
            pht  = fdot2_acc(hh[k], t2[k], pht);
            phr  = fdot2_acc(hh[k], r2[k], phr);
            ptr_ = fdot2_acc(t2[k], r2[k], ptr_);
        }
        float ht  = rsum8(pht);
        float hr  = rsum8(phr);
        float ttr = rsum8(ptr_);

        float sct, y2t, scr, y2r;
        if constexpr (HOP2) {
            sct = tv.x; y2t = tv.y;
            scr = rv.x; y2r = rv.y;
        } else {
            float tht = tanh_fast(ilam * tv.x);
            sct = tht * tv.y;  y2t = tht * tht;
            float thr_ = tanh_fast(ilam * rv.x);
            scr = thr_ * rv.y; y2r = thr_ * thr_;
        }

        float xyt = scp * sct * ht;
        float xyr = scp * scr * hr;

        float alt  = fmaf(2.f, xyt, 1.f + y2t);
        float dent = fmaxf(fmaf(p2, y2t, fmaf(2.f, xyt, 1.f)), MIN_NORM);
        float alr  = fmaf(2.f, xyr, 1.f + y2r);
        float denr = fmaxf(fmaf(p2, y2r, fmaf(2.f, xyr, 1.f)), MIN_NORM);
        float iS   = RCPF(dent * denr);
        float idt  = iS * denr;
        float idr  = iS * dent;

        float a2 = (alt * alt * p2 + 2.f * alt * bet * xyt + bet * bet * y2t) * idt * idt;
        float pa = fmaf(bet, xyt, alt * p2) * idt;
        float b2 = (alr * alr * p2 + 2.f * alr * bet * xyr + bet * bet * y2r) * idr * idr;
        float pb = fmaf(bet, xyr, alr * p2) * idr;

        float ytyr = sct * scr * ttr;
        float ab = (alt * alr * p2 + alt * bet * xyr + bet * alr * xyt + bet * bet * ytyr) * idt * idr;

        float am   = fmaf(2.f, ab, 1.f + b2);
        float bm   = 1.f - a2;
        float denm = fmaxf(fmaf(a2, b2, fmaf(2.f, ab, 1.f)), MIN_NORM);
        float idm  = RCPF(denm);
        float m2  = (am * am * a2 + 2.f * am * bm * ab + bm * bm * b2) * idm * idm;
        float pmv = fmaf(am, pa, bm * pb) * idm;

        const float maxn  = 1.f - 4e-3f;
        const float maxn2 = maxn * maxn;
        float irm = RSQF(fmaxf(m2, 1e-30f));
        float sc  = (m2 > maxn2) ? (maxn * irm) : 1.f;
        m2  *= sc * sc;
        pmv *= sc;

        float cs   = fmaf(-2.f, pmv, 1.f + m2);
        float dens = fmaxf(fmaf(p2, m2, fmaf(-2.f, pmv, 1.f)), MIN_NORM);
        float ids  = RCPF(dens);
        float s2  = fmaxf((cs * cs * p2 - 2.f * cs * bet * pmv + bet * bet * m2) * ids * ids, 1e-30f);
        float irs = RSQF(s2);
        float ns  = s2 * irs;
        float xa  = fminf(ns, 1.f - 1e-7f);
        float ath = 0.5f * __logf((1.f + xa) * RCPF(1.f - xa));
        float lgs = bet * ath * irs;

        float X  = am * idt;
        float Y  = bm * idr;
        float G  = idm * sc;
        float W  = lgs * ids;
        float WG = W * G;
        float Kt = WG * X * bet2 * sct;
        float Kr = WG * Y * bet2 * scr;
        float Z  = WG * bet * fmaf(X, alt, Y * alr);
        float Kh = scp * (Z - W * cs);

#pragma unroll
        for (int k = 0; k < 4; ++k) {
            float2 ft = __half22float2(t2[k]);
            float2 fr = __half22float2(r2[k]);
            acc[2 * k]     += fmaxf(fmaf(Kh, hv[2 * k],     fmaf(Kt, ft.x, Kr * fr.x)), 0.f);
            acc[2 * k + 1] += fmaxf(fmaf(Kh, hv[2 * k + 1], fmaf(Kt, ft.y, Kr * fr.y)), 0.f);
        }
    };

    int i = beg;
    if (i < end) {
        LD(i, tA, rA, tvA, rvA);
        while (true) {
            if (i + 1 < end) LD(i + 1, tB, rB, tvB, rvB);
            COMPUTE(tA, rA, tvA, rvA);
            ++i;
            if (i >= end) break;
            if (i + 1 < end) LD(i + 1, tA, rA, tvA, rvA);
            COMPUTE(tB, rB, tvB, rvB);
            ++i;
            if (i >= end) break;
        }
    }

    if (!act) return;

    float pn = 0.f;
#pragma unroll
    for (int k = 0; k < 8; ++k) pn += acc[k] * acc[k];
    float n2 = rsum8(pn);
    float sn = SQRTF(n2);
    float inv = RCPF(fmaxf(sn, 1e-12f));

    if constexpr (HOP2) {
        const float4* en = reinterpret_cast<const float4*>(entf + (size_t)h * 64 + 8 * l);
        float4 e0 = en[0], e1 = en[1];
        float4 o0, o1;
        o0.x = fmaf(0.25f, e0.x, fmaf(0.5f, hv[0], acc[0] * inv));
        o0.y = fmaf(0.25f, e0.y, fmaf(0.5f, hv[1], acc[1] * inv));
        o0.z = fmaf(0.25f, e0.z, fmaf(0.5f, hv[2], acc[2] * inv));
        o0.w = fmaf(0.25f, e0.w, fmaf(0.5f, hv[3], acc[3] * inv));
        o1.x = fmaf(0.25f, e1.x, fmaf(0.5f, hv[4], acc[4] * inv));
        o1.y = fmaf(0.25f, e1.y, fmaf(0.5f, hv[5], acc[5] * inv));
        o1.z = fmaf(0.25f, e1.z, fmaf(0.5f, hv[6], acc[6] * inv));
        o1.w = fmaf(0.25f, e1.w, fmaf(0.5f, hv[7], acc[7] * inv));
        float4* dd = reinterpret_cast<float4*>(outf + (size_t)h * 64 + 8 * l);
        dd[0] = o0;
        dd[1] = o1;
    } else {
        float4 st;
        __half2 sp[4];
#pragma unroll
        for (int k = 0; k < 4; ++k)
            sp[k] = __floats2half2_rn(acc[2 * k] * inv, acc[2 * k + 1] * inv);
        __builtin_memcpy(&st, sp, 16);
        *reinterpret_cast<float4*>(Ah2w + (size_t)h * 32 + 4 * l) = st;
        if (l == 0) {
            float nv = sn * inv;
            float nt = fmaxf(nv, MIN_NORM);
            float tht2 = tanh_fast(ILAM2 * nt);
            Tt2w[h] = make_float2(tht2 * RCPF(nt), tht2 * tht2);
        }
    }
}

extern "C" void kernel_launch(void* const* d_in, const int* in_sizes, int n_in,
                              void* d_out, int out_size, void* d_ws, size_t ws_size,
                              hipStream_t stream)
{
    const float* ent   = (const float*)d_in[0];
    const float* rel   = (const float*)d_in[1];
    const int*   eidx  = (const int*)d_in[2];
    const int*   etype = (const int*)d_in[3];

    int E = in_sizes[3];
    int N = in_sizes[0] / 64;
    int NR = in_sizes[1] / 64;
    const int* head = eidx;
    const int* tail = eidx + E;

    double th1d = tanh(1.0);
    float SCP2  = (float)th1d;
    float P2C   = (float)(th1d * th1d);
    float ILAM2 = (float)(1.0 / (1.0 - th1d * th1d));

    int CAP = E / 8 + 8192;               // per-region queue capacity

    // ws layout (sizes match kernel indexing exactly):
    // EH2[N*32 h2] | Ah2[N*32 h2] | RelH2[NR*32 h2] | rec[E int] | BK[8*CAP int2]
    // | OC[N int2] | P[N] | C[N] DH[64] BCUR[8] (one memset) | T[N] | BS[1024]
    // | DB[64] | perm[N] | Th1,Tt1,Tt2[N f2] | RelC1,RelC2[NR f2]
    __half2* EH2   = (__half2*)d_ws;                       // 25.6 MB
    __half2* Ah2   = EH2 + (size_t)N * 32;                 // 25.6 MB
    __half2* RelH2 = Ah2 + (size_t)N * 32;
    int*     rec   = (int*)(RelH2 + (size_t)NR * 32);      // 4 MB
    int2*    BK    = (int2*)(rec + E);                     // 8*CAP int2 ~ 8.5 MB
    int2*    OC    = BK + (size_t)8 * CAP;
    int*     P     = (int*)(OC + N);
    int*     C     = P + N;
    int*     DH    = C + N;
    int*     BCUR  = DH + 64;
    int*     T     = BCUR + 8;
    int*     BS    = T + N;
    int*     DB    = BS + 1024;
    int*     perm  = DB + 64;
    float2*  Th1   = (float2*)(perm + N);
    float2*  Tt1   = Th1 + N;
    float2*  Tt2   = Tt1 + N;
    float2*  RelC1 = Tt2 + N;
    float2*  RelC2 = RelC1 + NR;

    int NB = (N + 255) / 256;
    int EB = (E + 255) / 256;
    int PG = (N * 16 + 255) / 256;
    int RG = (NR * 16 + 255) / 256;
    int RSZ = (N + 7) / 8;
    const int S = 32;                     // scatter2 blocks per region

    float* out = (float*)d_out;
    dim3 blk(256);
    int hopGrid = (N * 8 + 255) / 256;

    // one memset covers C[N] + DH[64] + BCUR[8]
    (void)hipMemsetAsync(C, 0, (size_t)(N + 72) * sizeof(int), stream);

    k_pass1<<<EB + PG + RG, blk, 0, stream>>>(
        head, (const float4*)ent, (const float4*)rel,
        C, Th1, Tt1, RelC1, RelC2, EH2, RelH2, ILAM2, E, N, NR, EB, PG);

    k_scan1<<<NB, blk, 0, stream>>>(C, T, BS, DH, N);
    k_scan2<<<2, 1024, 0, stream>>>(BS, DH, DB, NB);
    k_scan3<<<NB, blk, 0, stream>>>(C, T, BS, OC, P, N);

    k_bucket<<<NB + EB, blk, 0, stream>>>(
        C, DB, perm, head, tail, etype, P, rec, BCUR, BK, N, E, NB, RSZ, CAP);

    k_scatter2<<<8 * S, blk, 0, stream>>>(BK, BCUR, P, rec, CAP, S);

    rgat_hop_kernel<false><<<hopGrid, blk, 0, stream>>>(
        EH2, RelH2, Th1, Tt1, Tt2, RelC1, RelC2, rec, OC, perm,
        nullptr, nullptr, Ah2, Tt2, SCP2, P2C, ILAM2, N);

    rgat_hop_kernel<true><<<hopGrid, blk, 0, stream>>>(
        Ah2, RelH2, Th1, Tt1, Tt2, RelC1, RelC2, rec, OC, perm,
        ent, out, nullptr, nullptr, SCP2, P2C, ILAM2, N);
}

// Round 23
// 250.049 us; speedup vs baseline: 6.8000x; 6.8000x over previous
//
#include <hip/hip_runtime.h>
#include <hip/hip_fp16.h>
#include <cmath>

#define MIN_NORM 1e-15f
#define RCPF(x)  __builtin_amdgcn_rcpf(x)
#define SQRTF(x) __builtin_amdgcn_sqrtf(x)
#define RSQF(x)  __builtin_amdgcn_rsqf(x)

#if defined(__has_builtin)
#if __has_builtin(__builtin_amdgcn_fdot2)
#define HAVE_FDOT2 1
#endif
#endif

typedef _Float16 h2_t __attribute__((ext_vector_type(2)));

__device__ __forceinline__ float fdot2_acc(__half2 a, __half2 b, float c) {
#ifdef HAVE_FDOT2
    h2_t av, bv;
    __builtin_memcpy(&av, &a, 4);
    __builtin_memcpy(&bv, &b, 4);
    return __builtin_amdgcn_fdot2(av, bv, c, false);
#else
    float2 fa = __half22float2(a);
    float2 fb = __half22float2(b);
    return fmaf(fa.x, fb.x, fmaf(fa.y, fb.y, c));
#endif
}

template<int CTRL>
__device__ __forceinline__ float dpp_add(float v) {
    return __int_as_float(__builtin_amdgcn_update_dpp(0, __float_as_int(v), CTRL, 0xF, 0xF, false));
}

__device__ __forceinline__ float rsum16(float v) {
    v += dpp_add<0x121>(v);
    v += dpp_add<0x122>(v);
    v += dpp_add<0x124>(v);
    v += dpp_add<0x128>(v);
    return v;
}

__device__ __forceinline__ float rsum8(float v) {
    v += dpp_add<0xB1>(v);   // quad_perm xor1
    v += dpp_add<0x4E>(v);   // quad_perm xor2
    v += dpp_add<0x141>(v);  // row_half_mirror
    return v;
}

__device__ __forceinline__ float tanh_fast(float x) {
    float ex = __expf(fminf(2.f * x, 30.f));
    return (ex - 1.f) * RCPF(ex + 1.f);
}

// ---- fused pass 1: [0,EB) count | [EB,EB+PG) entity tables + EH | rest rel ----
__global__ __launch_bounds__(256) void k_pass1(
    const int*    __restrict__ head,
    const float4* __restrict__ ent,
    const float4* __restrict__ rel,
    int*     __restrict__ C,
    float2*  __restrict__ Th1,
    float2*  __restrict__ Tt1,
    float2*  __restrict__ RelC1,
    float2*  __restrict__ RelC2,
    __half2* __restrict__ EH2,     // [N*32]
    __half2* __restrict__ RelH2,   // [NR*32]
    float ILAM2, int E, int N, int NR, int EB, int PG)
{
    int b = (int)blockIdx.x;
    if (b < EB) {
        int i = b * 256 + (int)threadIdx.x;
        if (i < E) atomicAdd(&C[head[i]], 1);
    } else if (b < EB + PG) {
        int gid = ((b - EB) * 256 + (int)threadIdx.x) >> 4;
        int g   = (int)threadIdx.x & 15;
        if (gid >= N) return;
        float4 v = ent[(size_t)gid * 16 + g];
        EH2[(size_t)gid * 32 + 2 * g]     = __floats2half2_rn(v.x, v.y);
        EH2[(size_t)gid * 32 + 2 * g + 1] = __floats2half2_rn(v.z, v.w);
        float n2 = rsum16(v.x * v.x + v.y * v.y + v.z * v.z + v.w * v.w);
        if (g == 0) {
            float nh     = fmaxf(SQRTF(fmaxf(n2, 0.f)), MIN_NORM);
            float inv_nh = RCPF(nh);
            float th     = tanh_fast(nh);
            Th1[gid] = make_float2(th * inv_nh, th * th);
            Tt1[gid] = make_float2(nh, inv_nh);
        }
    } else {
        int gid = ((b - EB - PG) * 256 + (int)threadIdx.x) >> 4;
        int g   = (int)threadIdx.x & 15;
        if (gid >= NR) return;
        float4 v = rel[(size_t)gid * 16 + g];
        RelH2[(size_t)gid * 32 + 2 * g]     = __floats2half2_rn(v.x, v.y);
        RelH2[(size_t)gid * 32 + 2 * g + 1] = __floats2half2_rn(v.z, v.w);
        float n2 = rsum16(v.x * v.x + v.y * v.y + v.z * v.z + v.w * v.w);
        if (g == 0) {
            float nr = fmaxf(SQRTF(n2), MIN_NORM);
            float inv_nr = RCPF(nr);
            RelC1[gid] = make_float2(nr, inv_nr);
            float thr2 = tanh_fast(ILAM2 * nr);
            RelC2[gid] = make_float2(thr2 * inv_nr, thr2 * thr2);
        }
    }
}

// ---- scan1: per-block inclusive scan C -> T, block sums -> BS, + degree hist ----
__global__ __launch_bounds__(256) void k_scan1(const int* __restrict__ C,
                                               int* __restrict__ T,
                                               int* __restrict__ BS,
                                               int* __restrict__ DH, int N) {
    __shared__ int lds[256];
    __shared__ int lh[64];
    if (threadIdx.x < 64) lh[threadIdx.x] = 0;
    int i = blockIdx.x * 256 + (int)threadIdx.x;
    int v = (i < N) ? C[i] : 0;
    lds[threadIdx.x] = v;
    __syncthreads();
    for (int off = 1; off < 256; off <<= 1) {
        int add = (threadIdx.x >= (unsigned)off) ? lds[threadIdx.x - off] : 0;
        __syncthreads();
        lds[threadIdx.x] += add;
        __syncthreads();
    }
    if (i < N) {
        T[i] = lds[threadIdx.x];
        int bd = 63 - min(v, 63);
        atomicAdd(&lh[bd], 1);
    }
    if (threadIdx.x == 255) BS[blockIdx.x] = lds[255];
    __syncthreads();
    if (threadIdx.x < 64 && lh[threadIdx.x] > 0)
        atomicAdd(&DH[threadIdx.x], lh[threadIdx.x]);
}

// ---- scan2: block 0 scans BS[nb]; block 1 scans DH->DB ----
__global__ __launch_bounds__(1024) void k_scan2(int* __restrict__ BS,
                                                const int* __restrict__ DH,
                                                int* __restrict__ DB, int nb) {
    if (blockIdx.x == 0) {
        __shared__ int lds[1024];
        int v = ((int)threadIdx.x < nb) ? BS[threadIdx.x] : 0;
        lds[threadIdx.x] = v;
        __syncthreads();
        for (int off = 1; off < 1024; off <<= 1) {
            int add = (threadIdx.x >= (unsigned)off) ? lds[threadIdx.x - off] : 0;
            __syncthreads();
            lds[threadIdx.x] += add;
            __syncthreads();
        }
        if ((int)threadIdx.x < nb) BS[threadIdx.x] = lds[threadIdx.x] - v;
    } else {
        __shared__ int lds[64];
        if (threadIdx.x >= 64) return;
        int t = (int)threadIdx.x;
        int v = DH[t];
        lds[t] = v;
        __syncthreads();
        for (int off = 1; off < 64; off <<= 1) {
            int add = (t >= off) ? lds[t - off] : 0;
            __syncthreads();
            lds[t] += add;
            __syncthreads();
        }
        DB[t] = lds[t] - v;
    }
}

// ---- scan3: ordered offsets OC={beg,cnt}, P=beg ----
__global__ __launch_bounds__(256) void k_scan3(const int* __restrict__ C,
                                               const int* __restrict__ T,
                                               const int* __restrict__ BS,
                                               int2* __restrict__ OC,
                                               int* __restrict__ P, int N) {
    int i = blockIdx.x * 256 + (int)threadIdx.x;
    if (i < N) {
        int c = C[i];
        int beg = T[i] - c + BS[blockIdx.x];
        OC[i] = make_int2(beg, c);
        P[i] = beg;
    }
}

// ---- fused pass 2: [0,NB) perm dscatter | [NB,..) region-routed edge scatter ----
__global__ __launch_bounds__(256) void k_pass2(
    const int* __restrict__ C,
    int*       __restrict__ DB,
    int*       __restrict__ perm,
    const int* __restrict__ head,
    const int* __restrict__ tail,
    const int* __restrict__ etype,
    int*       __restrict__ P,
    int*       __restrict__ rec,
    int N, int E, int NB, int SLICES)
{
    int b = (int)blockIdx.x;
    if (b < NB) {
        __shared__ int lh[64];
        __shared__ int lbase[64];
        if (threadIdx.x < 64) lh[threadIdx.x] = 0;
        __syncthreads();
        int i = b * 256 + (int)threadIdx.x;
        int bd = -1, lr = 0;
        if (i < N) {
            bd = 63 - min(C[i], 63);
            lr = atomicAdd(&lh[bd], 1);
        }
        __syncthreads();
        if (threadIdx.x < 64 && lh[threadIdx.x] > 0)
            lbase[threadIdx.x] = atomicAdd(&DB[threadIdx.x], lh[threadIdx.x]);
        __syncthreads();
        if (bd >= 0) perm[lbase[bd] + lr] = i;
    } else {
        int region = b & 7;
        int slice  = (b - NB) >> 3;
        int rlo = (int)(((long long)region * N) >> 3);
        int rhi = (int)(((long long)(region + 1) * N) >> 3);
        int step = 256 * SLICES;
        for (int i = slice * 256 + (int)threadIdx.x; i < E; i += step) {
            int h = head[i];
            int t = tail[i];
            int et = etype[i];
            if (h >= rlo && h < rhi) {
                int pos = atomicAdd(&P[h], 1);
                rec[pos] = t | ((et - 1) << 20);
            }
        }
    }
}

// ---- hop kernel: 8-lane group/head; CONTIGUOUS dims {8l..8l+7}, one dwordx4
//      per row; 2-deep pipeline; fdot2 dots; fused epilogue ----
template<bool HOP2>
__global__ __launch_bounds__(256) void rgat_hop_kernel(
    const __half2* __restrict__ e2,     // hop1: EH2; hop2: Ah2 (32 half2/row)
    const __half2* __restrict__ rel2,
    const float2*  __restrict__ Th1,
    const float2*  __restrict__ Tt1,
    const float2*  __restrict__ Tt2,
    const float2*  __restrict__ RelC1,
    const float2*  __restrict__ RelC2,
    const int*     __restrict__ rec,
    const int2*    __restrict__ OC,
    const int*     __restrict__ perm,
    const float*   __restrict__ entf,   // hop2 only
    float*         __restrict__ outf,   // hop2 only
    __half2*       __restrict__ Ah2w,   // hop1 only
    float2*        __restrict__ Tt2w,   // hop1 only
    float SCP2, float P2C, float ILAM2, int N)
{
    int tid  = blockIdx.x * 256 + (int)threadIdx.x;
    int slot = tid >> 3;
    int l    = (int)threadIdx.x & 7;
    bool act = slot < N;
    int h    = perm[act ? slot : 0];

    int2 oc = OC[h];
    int beg = act ? oc.x : 0;
    int end = act ? (oc.x + oc.y) : 0;

    // head row: one dwordx4 (8 contiguous halfs = dims 8l..8l+7)
    float4 hraw = *reinterpret_cast<const float4*>(e2 + (size_t)h * 32 + 4 * l);
    __half2 hh[4];
    float hv[8];
    {
        __builtin_memcpy(hh, &hraw, 16);
#pragma unroll
        for (int k = 0; k < 4; ++k) {
            float2 f = __half22float2(hh[k]);
            hv[2 * k] = f.x; hv[2 * k + 1] = f.y;
        }
    }

    float scp, p2;
    if constexpr (HOP2) {
        scp = SCP2; p2 = P2C;
    } else {
        float2 th = Th1[h];
        scp = th.x; p2 = th.y;
    }
    float bet  = fmaxf(1.f - p2, MIN_NORM);
    float ilam = RCPF(bet);
    float bet2 = bet * bet;

    float acc[8];
#pragma unroll
    for (int k = 0; k < 8; ++k) acc[k] = 0.f;

    float4 tA, rA, tB, rB;
    float2 tvA, rvA, tvB, rvB;

    auto LD = [&](int i, float4& T4, float4& R4, float2& TV, float2& RV) {
        int rc = rec[i];
        int ti = rc & 0xFFFFF;
        int ri = rc >> 20;
        T4 = *reinterpret_cast<const float4*>(e2   + (size_t)ti * 32 + 4 * l);
        R4 = *reinterpret_cast<const float4*>(rel2 + (size_t)ri * 32 + 4 * l);
        if constexpr (HOP2) { TV = Tt2[ti]; RV = RelC2[ri]; }
        else               { TV = Tt1[ti]; RV = RelC1[ri]; }
    };

    auto COMPUTE = [&](const float4& T4, const float4& R4, float2 tv, float2 rv) {
        __half2 t2[4], r2[4];
        __builtin_memcpy(t2, &T4, 16);
        __builtin_memcpy(r2, &R4, 16);

        float pht = 0.f, phr = 0.f, ptr_ = 0.f;
#pragma unroll
        for (int k = 0; k < 4; ++k) {
            pht  = fdot2_acc(hh[k], t2[k], pht);
            phr  = fdot2_acc(hh[k], r2[k], phr);
            ptr_ = fdot2_acc(t2[k], r2[k], ptr_);
        }
        float ht  = rsum8(pht);
        float hr  = rsum8(phr);
        float ttr = rsum8(ptr_);

        float sct, y2t, scr, y2r;
        if constexpr (HOP2) {
            sct = tv.x; y2t = tv.y;
            scr = rv.x; y2r = rv.y;
        } else {
            float tht = tanh_fast(ilam * tv.x);
            sct = tht * tv.y;  y2t = tht * tht;
            float thr_ = tanh_fast(ilam * rv.x);
            scr = thr_ * rv.y; y2r = thr_ * thr_;
        }

        float xyt = scp * sct * ht;
        float xyr = scp * scr * hr;

        float alt  = fmaf(2.f, xyt, 1.f + y2t);
        float dent = fmaxf(fmaf(p2, y2t, fmaf(2.f, xyt, 1.f)), MIN_NORM);
        float alr  = fmaf(2.f, xyr, 1.f + y2r);
        float denr = fmaxf(fmaf(p2, y2r, fmaf(2.f, xyr, 1.f)), MIN_NORM);
        float iS   = RCPF(dent * denr);
        float idt  = iS * denr;
        float idr  = iS * dent;

        float a2 = (alt * alt * p2 + 2.f * alt * bet * xyt + bet * bet * y2t) * idt * idt;
        float pa = fmaf(bet, xyt, alt * p2) * idt;
        float b2 = (alr * alr * p2 + 2.f * alr * bet * xyr + bet * bet * y2r) * idr * idr;
        float pb = fmaf(bet, xyr, alr * p2) * idr;

        float ytyr = sct * scr * ttr;
        float ab = (alt * alr * p2 + alt * bet * xyr + bet * alr * xyt + bet * bet * ytyr) * idt * idr;

        float am   = fmaf(2.f, ab, 1.f + b2);
        float bm   = 1.f - a2;
        float denm = fmaxf(fmaf(a2, b2, fmaf(2.f, ab, 1.f)), MIN_NORM);
        float idm  = RCPF(denm);
        float m2  = (am * am * a2 + 2.f * am * bm * ab + bm * bm * b2) * idm * idm;
        float pmv = fmaf(am, pa, bm * pb) * idm;

        const float maxn  = 1.f - 4e-3f;
        const float maxn2 = maxn * maxn;
        float irm = RSQF(fmaxf(m2, 1e-30f));
        float sc  = (m2 > maxn2) ? (maxn * irm) : 1.f;
        m2  *= sc * sc;
        pmv *= sc;

        float cs   = fmaf(-2.f, pmv, 1.f + m2);
        float dens = fmaxf(fmaf(p2, m2, fmaf(-2.f, pmv, 1.f)), MIN_NORM);
        float ids  = RCPF(dens);
        float s2  = fmaxf((cs * cs * p2 - 2.f * cs * bet * pmv + bet * bet * m2) * ids * ids, 1e-30f);
        float irs = RSQF(s2);
        float ns  = s2 * irs;
        float xa  = fminf(ns, 1.f - 1e-7f);
        float ath = 0.5f * __logf((1.f + xa) * RCPF(1.f - xa));
        float lgs = bet * ath * irs;

        float X  = am * idt;
        float Y  = bm * idr;
        float G  = idm * sc;
        float W  = lgs * ids;
        float WG = W * G;
        float Kt = WG * X * bet2 * sct;
        float Kr = WG * Y * bet2 * scr;
        float Z  = WG * bet * fmaf(X, alt, Y * alr);
        float Kh = scp * (Z - W * cs);

#pragma unroll
        for (int k = 0; k < 4; ++k) {
            float2 ft = __half22float2(t2[k]);
            float2 fr = __half22float2(r2[k]);
            acc[2 * k]     += fmaxf(fmaf(Kh, hv[2 * k],     fmaf(Kt, ft.x, Kr * fr.x)), 0.f);
            acc[2 * k + 1] += fmaxf(fmaf(Kh, hv[2 * k + 1], fmaf(Kt, ft.y, Kr * fr.y)), 0.f);
        }
    };

    int i = beg;
    if (i < end) {
        LD(i, tA, rA, tvA, rvA);
        while (true) {
            if (i + 1 < end) LD(i + 1, tB, rB, tvB, rvB);
            COMPUTE(tA, rA, tvA, rvA);
            ++i;
            if (i >= end) break;
            if (i + 1 < end) LD(i + 1, tA, rA, tvA, rvA);
            COMPUTE(tB, rB, tvB, rvB);
            ++i;
            if (i >= end) break;
        }
    }

    if (!act) return;

    float pn = 0.f;
#pragma unroll
    for (int k = 0; k < 8; ++k) pn += acc[k] * acc[k];
    float n2 = rsum8(pn);
    float sn = SQRTF(n2);
    float inv = RCPF(fmaxf(sn, 1e-12f));

    if constexpr (HOP2) {
        const float4* en = reinterpret_cast<const float4*>(entf + (size_t)h * 64 + 8 * l);
        float4 e0 = en[0], e1 = en[1];
        float4 o0, o1;
        o0.x = fmaf(0.25f, e0.x, fmaf(0.5f, hv[0], acc[0] * inv));
        o0.y = fmaf(0.25f, e0.y, fmaf(0.5f, hv[1], acc[1] * inv));
        o0.z = fmaf(0.25f, e0.z, fmaf(0.5f, hv[2], acc[2] * inv));
        o0.w = fmaf(0.25f, e0.w, fmaf(0.5f, hv[3], acc[3] * inv));
        o1.x = fmaf(0.25f, e1.x, fmaf(0.5f, hv[4], acc[4] * inv));
        o1.y = fmaf(0.25f, e1.y, fmaf(0.5f, hv[5], acc[5] * inv));
        o1.z = fmaf(0.25f, e1.z, fmaf(0.5f, hv[6], acc[6] * inv));
        o1.w = fmaf(0.25f, e1.w, fmaf(0.5f, hv[7], acc[7] * inv));
        float4* dd = reinterpret_cast<float4*>(outf + (size_t)h * 64 + 8 * l);
        dd[0] = o0;
        dd[1] = o1;
    } else {
        float4 st;
        __half2 sp[4];
#pragma unroll
        for (int k = 0; k < 4; ++k)
            sp[k] = __floats2half2_rn(acc[2 * k] * inv, acc[2 * k + 1] * inv);
        __builtin_memcpy(&st, sp, 16);
        *reinterpret_cast<float4*>(Ah2w + (size_t)h * 32 + 4 * l) = st;
        if (l == 0) {
            float nv = sn * inv;
            float nt = fmaxf(nv, MIN_NORM);
            float tht2 = tanh_fast(ILAM2 * nt);
            Tt2w[h] = make_float2(tht2 * RCPF(nt), tht2 * tht2);
        }
    }
}

extern "C" void kernel_launch(void* const* d_in, const int* in_sizes, int n_in,
                              void* d_out, int out_size, void* d_ws, size_t ws_size,
                              hipStream_t stream)
{
    const float* ent   = (const float*)d_in[0];
    const float* rel   = (const float*)d_in[1];
    const int*   eidx  = (const int*)d_in[2];
    const int*   etype = (const int*)d_in[3];

    int E = in_sizes[3];
    int N = in_sizes[0] / 64;
    int NR = in_sizes[1] / 64;
    const int* head = eidx;
    const int* tail = eidx + E;

    double th1d = tanh(1.0);
    float SCP2  = (float)th1d;
    float P2C   = (float)(th1d * th1d);
    float ILAM2 = (float)(1.0 / (1.0 - th1d * th1d));

    __half2* EH2   = (__half2*)d_ws;                       // 25.6 MB
    __half2* Ah2   = EH2 + (size_t)N * 32;                 // 25.6 MB
    __half2* RelH2 = Ah2 + (size_t)N * 32;
    int*     rec   = (int*)(RelH2 + (size_t)NR * 32);      // 4 MB
    int2*    OC    = (int2*)(rec + E);
    int*     P     = (int*)(OC + N);
    int*     C     = P + N;
    int*     DH    = C + N;
    int*     T     = DH + 64;
    int*     BS    = T + N;
    int*     DB    = BS + 1024;
    int*     perm  = DB + 64;
    float2*  Th1   = (float2*)(perm + N);
    float2*  Tt1   = Th1 + N;
    float2*  Tt2   = Tt1 + N;
    float2*  RelC1 = Tt2 + N;
    float2*  RelC2 = RelC1 + NR;

    int NB = (N + 255) / 256;
    int EB = (E + 255) / 256;
    int PG = (N * 16 + 255) / 256;
    int RG = (NR * 16 + 255) / 256;
    const int SLICES = 104;

    float* out = (float*)d_out;
    dim3 blk(256);
    int hopGrid = (N * 8 + 255) / 256;

    (void)hipMemsetAsync(C, 0, (size_t)(N + 64) * sizeof(int), stream);

    k_pass1<<<EB + PG + RG, blk, 0, stream>>>(
        head, (const float4*)ent, (const float4*)rel,
        C, Th1, Tt1, RelC1, RelC2, EH2, RelH2, ILAM2, E, N, NR, EB, PG);

    k_scan1<<<NB, blk, 0, stream>>>(C, T, BS, DH, N);
    k_scan2<<<2, 1024, 0, stream>>>(BS, DH, DB, NB);
    k_scan3<<<NB, blk, 0, stream>>>(C, T, BS, OC, P, N);

    k_pass2<<<NB + 8 * SLICES, blk, 0, stream>>>(
        C, DB, perm, head, tail, etype, P, rec, N, E, NB, SLICES);

    rgat_hop_kernel<false><<<hopGrid, blk, 0, stream>>>(
        EH2, RelH2, Th1, Tt1, Tt2, RelC1, RelC2, rec, OC, perm,
        nullptr, nullptr, Ah2, Tt2, SCP2, P2C, ILAM2, N);

    rgat_hop_kernel<true><<<hopGrid, blk, 0, stream>>>(
        Ah2, RelH2, Th1, Tt1, Tt2, RelC1, RelC2, rec, OC, perm,
        ent, out, nullptr, nullptr, SCP2, P2C, ILAM2, N);
}